// Round 15
// baseline (257.485 us; speedup 1.0000x reference)
//
#include <hip/hip_runtime.h>
#include <math.h>

#define B_ 4
#define C_ 256
#define CI_ 128
#define N_ 4096
#define QT_ 128
#define KT_ 64
#define KH_ 2048
#define NITER (KH_ / KT_)     // 32
#define KSTRIDE 264   // 256 + 8 pad (verified round 3)
#define VSTRIDE 72    // 64 + 8 pad (verified round 3)
constexpr float EPS_ = 1e-5f;

typedef __attribute__((ext_vector_type(8))) short bfrag;
typedef __attribute__((ext_vector_type(4))) float f4;

__device__ __forceinline__ unsigned short bf16r(float x) {
    unsigned u = __float_as_uint(x);
    u += 0x7FFFu + ((u >> 16) & 1u);
    return (unsigned short)(u >> 16);
}
__device__ __forceinline__ unsigned pack_bf16(float a, float b) {
    unsigned ua = __float_as_uint(a); ua += 0x7FFFu + ((ua >> 16) & 1u);
    unsigned ub = __float_as_uint(b); ub += 0x7FFFu + ((ub >> 16) & 1u);
    return (ua >> 16) | (ub & 0xFFFF0000u);
}

// ---------------- K2: fused g conv + xt transpose (BALANCED) -------------
// R14's y==0-concentrated xt write made 1/16 of blocks ~2x slower (tail).
// Fix: block y writes only its own c-range (c0>>4 == y: two 8-chunks =
// 32 B/thread, uniform). Union over y covers all 256 c exactly once;
// same pack_bf16 on same loads -> bit-identical xt.
__global__ __launch_bounds__(256) void gconv_xt(const float* __restrict__ x,
                                                const float* __restrict__ gw,
                                                const float* __restrict__ gb,
                                                unsigned short* __restrict__ xt,
                                                unsigned short* __restrict__ gx) {
    int m  = blockIdx.x * 256 + threadIdx.x;
    int o0 = blockIdx.y * 8;
    int b  = blockIdx.z;
    const int yown = blockIdx.y;                 // owns c0 in [16y, 16y+16)
    const float* xb = x + (size_t)b * C_ * N_;
    unsigned short* xtr = xt + ((size_t)b * N_ + m) * C_;
    float acc[8];
#pragma unroll
    for (int o = 0; o < 8; o++) acc[o] = gb[o0 + o];
    for (int c0 = 0; c0 < C_; c0 += 8) {
        float xv[8];
#pragma unroll
        for (int j = 0; j < 8; j++) xv[j] = xb[(c0 + j) * N_ + m];
        if ((c0 >> 4) == yown) {
            uint4 v;
            v.x = pack_bf16(xv[0], xv[1]);
            v.y = pack_bf16(xv[2], xv[3]);
            v.z = pack_bf16(xv[4], xv[5]);
            v.w = pack_bf16(xv[6], xv[7]);
            *(uint4*)&xtr[c0] = v;
        }
#pragma unroll
        for (int o = 0; o < 8; o++) {
            const float* wr = gw + (size_t)(o0 + o) * C_ + c0;
#pragma unroll
            for (int j = 0; j < 8; j++) acc[o] += wr[j] * xv[j];
        }
    }
#pragma unroll
    for (int o = 0; o < 8; o++)
        gx[((size_t)b * CI_ + o0 + o) * N_ + m] = bf16r(acc[o]);
}

// ---------------- K3: MFMA flash attention — R0-verbatim (112 µs) --------
__global__ __launch_bounds__(1024, 4) void attn(const unsigned short* __restrict__ xt,
                                                const unsigned short* __restrict__ gx,
                                                float* __restrict__ Yp,
                                                float* __restrict__ ml) {
    __shared__ __align__(16) unsigned short Ks[2][64 * KSTRIDE];    // 2 x 33 KB
    __shared__ __align__(16) unsigned short Vs[2][128 * VSTRIDE];   // 2 x 18 KB
    __shared__ __align__(16) unsigned short Ps[128 * VSTRIDE];      // 18 KB

    const int tid  = threadIdx.x;
    const int lane = tid & 63, w = tid >> 6;     // w in 0..15
    const int wq = w & 7, g = w >> 3;            // q-band, m-group
    const int quad = lane >> 4, ql = lane & 15;
    const int half = blockIdx.x & 1;
    const int b    = (blockIdx.x & 7) >> 1;
    const int qt   = blockIdx.x >> 3;
    const int n0   = qt * QT_;
    const int kbase = half * KH_;
    const unsigned short* xtb = xt + (size_t)b * N_ * C_;
    const unsigned short* gxb = gx + (size_t)b * CI_ * N_;

    bfrag qb[8];
#pragma unroll
    for (int ks = 0; ks < 8; ks++)
        qb[ks] = *(const bfrag*)(xtb + (size_t)(n0 + 16 * wq + ql) * C_ + 32 * ks + quad * 8);

    f4 yacc[8];
    const f4 zero4 = {0.f, 0.f, 0.f, 0.f};
#pragma unroll
    for (int i = 0; i < 8; i++) yacc[i] = zero4;
    float mrun = -INFINITY, lrun = 0.f;

    uint4 kreg[2], vreg[1];
#pragma unroll
    for (int r = 0; r < 2; r++) {
        int idx = r * 1024 + tid;
        kreg[r] = *(const uint4*)(xtb + (size_t)(kbase + (idx >> 5)) * C_ + (idx & 31) * 8);
    }
    vreg[0] = *(const uint4*)(gxb + (size_t)(tid >> 3) * N_ + kbase + (tid & 7) * 8);
#pragma unroll
    for (int r = 0; r < 2; r++) {
        int idx = r * 1024 + tid;
        *(uint4*)&Ks[0][(idx >> 5) * KSTRIDE + (idx & 31) * 8] = kreg[r];
    }
    *(uint4*)&Vs[0][(tid >> 3) * VSTRIDE + (tid & 7) * 8] = vreg[0];
#pragma unroll
    for (int r = 0; r < 2; r++) {
        int idx = r * 1024 + tid;
        kreg[r] = *(const uint4*)(xtb + (size_t)(kbase + KT_ + (idx >> 5)) * C_ + (idx & 31) * 8);
    }
    vreg[0] = *(const uint4*)(gxb + (size_t)(tid >> 3) * N_ + kbase + KT_ + (tid & 7) * 8);
    __syncthreads();                             // buf0 ready

    for (int it = 0; it < NITER; ++it) {
        const int cur = it & 1, nxt = cur ^ 1;

        if (it + 1 < NITER) {
#pragma unroll
            for (int r = 0; r < 2; r++) {
                int idx = r * 1024 + tid;
                *(uint4*)&Ks[nxt][(idx >> 5) * KSTRIDE + (idx & 31) * 8] = kreg[r];
            }
            *(uint4*)&Vs[nxt][(tid >> 3) * VSTRIDE + (tid & 7) * 8] = vreg[0];
        }
        if (it + 2 < NITER) {
            const int t0 = kbase + (it + 2) * KT_;
#pragma unroll
            for (int r = 0; r < 2; r++) {
                int idx = r * 1024 + tid;
                kreg[r] = *(const uint4*)(xtb + (size_t)(t0 + (idx >> 5)) * C_ + (idx & 31) * 8);
            }
            vreg[0] = *(const uint4*)(gxb + (size_t)(tid >> 3) * N_ + t0 + (tid & 7) * 8);
        }

        // ---- St = K.Q on this group's m-half : 16 mfma / wave ----
        f4 sacc[2];
        sacc[0] = zero4; sacc[1] = zero4;
#pragma unroll
        for (int ks = 0; ks < 8; ks++) {
            bfrag ka[2];
#pragma unroll
            for (int i = 0; i < 2; i++)
                ka[i] = *(const bfrag*)&Ks[cur][(32 * g + 16 * i + ql) * KSTRIDE + 32 * ks + quad * 8];
#pragma unroll
            for (int i = 0; i < 2; i++)
                sacc[i] = __builtin_amdgcn_mfma_f32_16x16x32_bf16(ka[i], qb[ks], sacc[i], 0, 0, 0);
        }

        // ---- group-local online softmax ----
        float mx = -INFINITY;
#pragma unroll
        for (int i = 0; i < 2; i++)
#pragma unroll
            for (int r = 0; r < 4; r++) mx = fmaxf(mx, sacc[i][r]);
        mx = fmaxf(mx, __shfl_xor(mx, 16, 64));
        mx = fmaxf(mx, __shfl_xor(mx, 32, 64));
        float mn = fmaxf(mrun, mx);
        float alpha = __expf(mrun - mn);       // -inf -> 0 first iter
        mrun = mn;
        lrun *= alpha;
        if (__any(alpha != 1.f)) {
#pragma unroll
            for (int i = 0; i < 8; i++) {
                yacc[i][0] *= alpha; yacc[i][1] *= alpha;
                yacc[i][2] *= alpha; yacc[i][3] *= alpha;
            }
        }

        // ---- P = exp(S-m) -> Ps[q][m], m in group's half (wave-private) ----
        {
            int q = 16 * wq + ql;
            float lsum = 0.f;
#pragma unroll
            for (int i = 0; i < 2; i++) {
                float p0 = __expf(sacc[i][0] - mrun);
                float p1 = __expf(sacc[i][1] - mrun);
                float p2 = __expf(sacc[i][2] - mrun);
                float p3 = __expf(sacc[i][3] - mrun);
                lsum += (p0 + p1) + (p2 + p3);
                int idx = q * VSTRIDE + 32 * g + 16 * i + 4 * quad;  // m = 32g+16i+4quad+r
                unsigned long long pv = (unsigned long long)pack_bf16(p0, p1)
                                      | ((unsigned long long)pack_bf16(p2, p3) << 32);
                *(unsigned long long*)&Ps[idx] = pv;
            }
            lrun += lsum;
        }

        // ---- Yt += Vt.P over group's m-half : 8 mfma / wave ----
        {
            bfrag pb, va[8];
            pb = *(const bfrag*)&Ps[(16 * wq + ql) * VSTRIDE + 32 * g + quad * 8];
#pragma unroll
            for (int i = 0; i < 8; i++)
                va[i] = *(const bfrag*)&Vs[cur][(16 * i + ql) * VSTRIDE + 32 * g + quad * 8];
#pragma unroll
            for (int i = 0; i < 8; i++)
                yacc[i] = __builtin_amdgcn_mfma_f32_16x16x32_bf16(va[i], pb, yacc[i], 0, 0, 0);
        }

        __syncthreads();   // buf[nxt] staged; buf[cur] + Ps reads done
    }

    // ---- epilogue: merge the two m-groups (split-K algebra), store ----
    lrun += __shfl_xor(lrun, 16, 64);
    lrun += __shfl_xor(lrun, 32, 64);

    float* PsF = (float*)Ps;          // Ps dead; 18432 B = 16 KB Ysc + 2 KB mlb
    float* Ysc = PsF;                 // [32 ci'][128 q]
    float* mlb = PsF + 4096;          // [2 g][128 q][2]

    const int q = 16 * wq + ql;
    if (quad == 0) {
        mlb[(g * 128 + q) * 2]     = mrun;
        mlb[(g * 128 + q) * 2 + 1] = lrun;
    }
    __syncthreads();
    float m0 = mlb[q * 2],           l0 = mlb[q * 2 + 1];
    float m1 = mlb[(128 + q) * 2],   l1 = mlb[(128 + q) * 2 + 1];
    float mm = fmaxf(m0, m1);
    float e0 = __expf(m0 - mm), e1 = __expf(m1 - mm);
    float lnew = e0 * l0 + e1 * l1;

#pragma unroll
    for (int c = 0; c < 4; c++) {                // ci chunks of 32
        if (g == 1) {
#pragma unroll
            for (int i2 = 0; i2 < 2; i2++) {
                int i = 2 * c + i2;
#pragma unroll
                for (int r = 0; r < 4; r++) {
                    int cip = 16 * i2 + 4 * quad + r;        // ci - 32c
                    Ysc[cip * 128 + q] = e1 * yacc[i][r];
                }
            }
        }
        __syncthreads();
        if (g == 0) {
#pragma unroll
            for (int i2 = 0; i2 < 2; i2++) {
                int i = 2 * c + i2;
#pragma unroll
                for (int r = 0; r < 4; r++) {
                    int ci = 16 * i + 4 * quad + r;
                    float v = e0 * yacc[i][r] + Ysc[(16 * i2 + 4 * quad + r) * 128 + q];
                    Yp[(((size_t)half * 4 + b) * CI_ + ci) * N_ + n0 + q] = v;
                }
            }
        }
        __syncthreads();
    }
    if (g == 0 && quad == 0) {
        ml[(((size_t)half * 4 + b) * N_ + n0 + q) * 2]     = mm;
        ml[(((size_t)half * 4 + b) * N_ + n0 + q) * 2 + 1] = lnew;
    }
}

// ---------------- K5: merged split-K + W conv + BN partials (R13) --------
__global__ __launch_bounds__(256) void wconv_stats(const float* __restrict__ Yp,
                                                   const float* __restrict__ ml,
                                                   const float* __restrict__ Ww,
                                                   const float* __restrict__ Wb,
                                                   float* __restrict__ wy,
                                                   float* __restrict__ part) {
    int n   = blockIdx.x * 256 + threadIdx.x;
    int co0 = blockIdx.y * 8;
    int b   = blockIdx.z;

    // split-K merge weights for this (b, n)
    float2 a0 = *(const float2*)&ml[((size_t)b * N_ + n) * 2];
    float2 a1 = *(const float2*)&ml[(((size_t)4 + b) * N_ + n) * 2];
    float mm = fmaxf(a0.x, a1.x);
    float e0 = __expf(a0.x - mm), e1 = __expf(a1.x - mm);
    float inv = 1.f / (e0 * a0.y + e1 * a1.y);
    float w0 = e0 * inv, w1 = e1 * inv;

    const float* y0b = Yp + (size_t)b * CI_ * N_;
    const float* y1b = Yp + (size_t)(4 + b) * CI_ * N_;
    float acc[8];
#pragma unroll
    for (int o = 0; o < 8; o++) acc[o] = Wb[co0 + o];
    for (int c0 = 0; c0 < CI_; c0 += 8) {
        float yv[8];
#pragma unroll
        for (int j = 0; j < 8; j++)
            yv[j] = w0 * y0b[(c0 + j) * N_ + n] + w1 * y1b[(c0 + j) * N_ + n];
#pragma unroll
        for (int o = 0; o < 8; o++) {
            const float* wr = Ww + (size_t)(co0 + o) * CI_ + c0;
#pragma unroll
            for (int j = 0; j < 8; j++) acc[o] += wr[j] * yv[j];
        }
    }
    float* wyb = wy + (size_t)b * C_ * N_;
#pragma unroll
    for (int o = 0; o < 8; o++) wyb[(co0 + o) * N_ + n] = acc[o];

    __shared__ float wred[16][4];
    int lane = threadIdx.x & 63, wid = threadIdx.x >> 6;
#pragma unroll
    for (int o = 0; o < 8; o++) {
        float s1 = acc[o], s2 = acc[o] * acc[o];
#pragma unroll
        for (int off = 32; off > 0; off >>= 1) {
            s1 += __shfl_down(s1, off, 64);
            s2 += __shfl_down(s2, off, 64);
        }
        if (lane == 0) { wred[o][wid] = s1; wred[8 + o][wid] = s2; }
    }
    __syncthreads();
    if (threadIdx.x < 16) {
        int qq = threadIdx.x;
        float tsum = wred[qq][0] + wred[qq][1] + wred[qq][2] + wred[qq][3];
        int o = qq & 7;
        int col = b * 16 + blockIdx.x;           // 0..63
        int slot = (qq < 8 ? co0 + o : 256 + co0 + o);
        part[(size_t)slot * 64 + col] = tsum;    // non-atomic, deterministic
    }
}

// ---------------- K6: BN finalize + residual (reduce folded, R11) --------
__global__ __launch_bounds__(256) void bn_finalize(float* __restrict__ wy,
                                                   const float* __restrict__ x,
                                                   const float* __restrict__ part,
                                                   const float* __restrict__ gamma,
                                                   const float* __restrict__ beta,
                                                   float* __restrict__ out) {
    int n4 = blockIdx.x * 256 + threadIdx.x;
    int co = blockIdx.y;
    int b  = blockIdx.z;

    __shared__ float red[2];
    {
        int lane = threadIdx.x & 63, wv = threadIdx.x >> 6;
        if (wv < 2) {
            int slot = (wv == 0) ? co : 256 + co;
            float v = part[(size_t)slot * 64 + lane];
#pragma unroll
            for (int off = 32; off > 0; off >>= 1) v += __shfl_down(v, off, 64);
            if (lane == 0) red[wv] = v;
        }
    }
    __syncthreads();

    float cnt  = (float)(B_ * N_);
    float mean = red[0] / cnt;
    float var  = red[1] / cnt - mean * mean;
    float sc   = rsqrtf(var + EPS_) * gamma[co];
    float bt   = beta[co];
    size_t idx = ((size_t)b * C_ + co) * N_ + (size_t)n4 * 4;
    float4 wv4 = *(const float4*)&wy[idx];
    float4 xv  = *(const float4*)&x[idx];
    float4 o;
    o.x = (wv4.x - mean) * sc + bt + xv.x;
    o.y = (wv4.y - mean) * sc + bt + xv.y;
    o.z = (wv4.z - mean) * sc + bt + xv.z;
    o.w = (wv4.w - mean) * sc + bt + xv.w;
    *(float4*)&out[idx] = o;
}

extern "C" void kernel_launch(void* const* d_in, const int* in_sizes, int n_in,
                              void* d_out, int out_size, void* d_ws, size_t ws_size,
                              hipStream_t stream) {
    const float* x     = (const float*)d_in[0];
    const float* gw    = (const float*)d_in[1];
    const float* gb    = (const float*)d_in[2];
    const float* Ww    = (const float*)d_in[3];
    const float* Wb    = (const float*)d_in[4];
    const float* gamma = (const float*)d_in[5];
    const float* beta  = (const float*)d_in[6];
    float* out = (float*)d_out;
    float* ws  = (float*)d_ws;

    // ws (floats): total 7,406,080 = 29.6 MB (round-3 proven footprint)
    unsigned short* xt  = (unsigned short*)ws;              // 8 MB
    unsigned short* gxb = (unsigned short*)(ws + 2097152);  // 4 MB
    float* Yp   = ws + 3145728;                             // 16 MB
    float* ml   = ws + 7340032;                             // 256 KB
    float* part = ws;            // 128 KB; aliases xt (dead after attn)
    float* wy   = out;                                      // aliased onto d_out

    hipLaunchKernelGGL(gconv_xt, dim3(16, 16, 4), dim3(256), 0, stream, x, gw, gb, xt, gxb);
    hipLaunchKernelGGL(attn, dim3(256), dim3(1024), 0, stream, xt, gxb, Yp, ml);
    hipLaunchKernelGGL(wconv_stats, dim3(16, 32, 4), dim3(256), 0, stream, Yp, ml, Ww, Wb, wy, part);
    hipLaunchKernelGGL(bn_finalize, dim3(4, 256, 4), dim3(256), 0, stream, wy, x, part, gamma, beta, out);
}

// Round 16
// 245.574 us; speedup vs baseline: 1.0485x; 1.0485x over previous
//
#include <hip/hip_runtime.h>
#include <math.h>

#define B_ 4
#define C_ 256
#define CI_ 128
#define N_ 4096
#define QT_ 128
#define KT_ 64
#define KH_ 2048
#define NITER (KH_ / KT_)     // 32
#define KSTRIDE 264   // 256 + 8 pad (verified round 3)
#define VSTRIDE 72    // 64 + 8 pad (verified round 3)
constexpr float EPS_ = 1e-5f;

typedef __attribute__((ext_vector_type(8))) short bfrag;
typedef __attribute__((ext_vector_type(4))) float f4;

__device__ __forceinline__ unsigned short bf16r(float x) {
    unsigned u = __float_as_uint(x);
    u += 0x7FFFu + ((u >> 16) & 1u);
    return (unsigned short)(u >> 16);
}
__device__ __forceinline__ unsigned pack_bf16(float a, float b) {
    unsigned ua = __float_as_uint(a); ua += 0x7FFFu + ((ua >> 16) & 1u);
    unsigned ub = __float_as_uint(b); ub += 0x7FFFu + ((ub >> 16) & 1u);
    return (ua >> 16) | (ub & 0xFFFF0000u);
}

// ---------------- K2: fused g conv + xt transpose (BALANCED) -------------
// R15-verbatim resubmit: R15's session ran 9.4% slow (attn 122.5 vs 111.9
// clock reference); clock-normalized non-attn was 123 vs R13's 134 -> the
// balanced fusion is a real ~11 µs win. Re-measuring under clean clocks.
// Block y writes only its own c-range (c0>>4 == y): 32 B/thread uniform;
// union over y covers all 256 c exactly once; bit-identical xt.
__global__ __launch_bounds__(256) void gconv_xt(const float* __restrict__ x,
                                                const float* __restrict__ gw,
                                                const float* __restrict__ gb,
                                                unsigned short* __restrict__ xt,
                                                unsigned short* __restrict__ gx) {
    int m  = blockIdx.x * 256 + threadIdx.x;
    int o0 = blockIdx.y * 8;
    int b  = blockIdx.z;
    const int yown = blockIdx.y;                 // owns c0 in [16y, 16y+16)
    const float* xb = x + (size_t)b * C_ * N_;
    unsigned short* xtr = xt + ((size_t)b * N_ + m) * C_;
    float acc[8];
#pragma unroll
    for (int o = 0; o < 8; o++) acc[o] = gb[o0 + o];
    for (int c0 = 0; c0 < C_; c0 += 8) {
        float xv[8];
#pragma unroll
        for (int j = 0; j < 8; j++) xv[j] = xb[(c0 + j) * N_ + m];
        if ((c0 >> 4) == yown) {
            uint4 v;
            v.x = pack_bf16(xv[0], xv[1]);
            v.y = pack_bf16(xv[2], xv[3]);
            v.z = pack_bf16(xv[4], xv[5]);
            v.w = pack_bf16(xv[6], xv[7]);
            *(uint4*)&xtr[c0] = v;
        }
#pragma unroll
        for (int o = 0; o < 8; o++) {
            const float* wr = gw + (size_t)(o0 + o) * C_ + c0;
#pragma unroll
            for (int j = 0; j < 8; j++) acc[o] += wr[j] * xv[j];
        }
    }
#pragma unroll
    for (int o = 0; o < 8; o++)
        gx[((size_t)b * CI_ + o0 + o) * N_ + m] = bf16r(acc[o]);
}

// ---------------- K3: MFMA flash attention — R0-verbatim (112 µs) --------
__global__ __launch_bounds__(1024, 4) void attn(const unsigned short* __restrict__ xt,
                                                const unsigned short* __restrict__ gx,
                                                float* __restrict__ Yp,
                                                float* __restrict__ ml) {
    __shared__ __align__(16) unsigned short Ks[2][64 * KSTRIDE];    // 2 x 33 KB
    __shared__ __align__(16) unsigned short Vs[2][128 * VSTRIDE];   // 2 x 18 KB
    __shared__ __align__(16) unsigned short Ps[128 * VSTRIDE];      // 18 KB

    const int tid  = threadIdx.x;
    const int lane = tid & 63, w = tid >> 6;     // w in 0..15
    const int wq = w & 7, g = w >> 3;            // q-band, m-group
    const int quad = lane >> 4, ql = lane & 15;
    const int half = blockIdx.x & 1;
    const int b    = (blockIdx.x & 7) >> 1;
    const int qt   = blockIdx.x >> 3;
    const int n0   = qt * QT_;
    const int kbase = half * KH_;
    const unsigned short* xtb = xt + (size_t)b * N_ * C_;
    const unsigned short* gxb = gx + (size_t)b * CI_ * N_;

    bfrag qb[8];
#pragma unroll
    for (int ks = 0; ks < 8; ks++)
        qb[ks] = *(const bfrag*)(xtb + (size_t)(n0 + 16 * wq + ql) * C_ + 32 * ks + quad * 8);

    f4 yacc[8];
    const f4 zero4 = {0.f, 0.f, 0.f, 0.f};
#pragma unroll
    for (int i = 0; i < 8; i++) yacc[i] = zero4;
    float mrun = -INFINITY, lrun = 0.f;

    uint4 kreg[2], vreg[1];
#pragma unroll
    for (int r = 0; r < 2; r++) {
        int idx = r * 1024 + tid;
        kreg[r] = *(const uint4*)(xtb + (size_t)(kbase + (idx >> 5)) * C_ + (idx & 31) * 8);
    }
    vreg[0] = *(const uint4*)(gxb + (size_t)(tid >> 3) * N_ + kbase + (tid & 7) * 8);
#pragma unroll
    for (int r = 0; r < 2; r++) {
        int idx = r * 1024 + tid;
        *(uint4*)&Ks[0][(idx >> 5) * KSTRIDE + (idx & 31) * 8] = kreg[r];
    }
    *(uint4*)&Vs[0][(tid >> 3) * VSTRIDE + (tid & 7) * 8] = vreg[0];
#pragma unroll
    for (int r = 0; r < 2; r++) {
        int idx = r * 1024 + tid;
        kreg[r] = *(const uint4*)(xtb + (size_t)(kbase + KT_ + (idx >> 5)) * C_ + (idx & 31) * 8);
    }
    vreg[0] = *(const uint4*)(gxb + (size_t)(tid >> 3) * N_ + kbase + KT_ + (tid & 7) * 8);
    __syncthreads();                             // buf0 ready

    for (int it = 0; it < NITER; ++it) {
        const int cur = it & 1, nxt = cur ^ 1;

        if (it + 1 < NITER) {
#pragma unroll
            for (int r = 0; r < 2; r++) {
                int idx = r * 1024 + tid;
                *(uint4*)&Ks[nxt][(idx >> 5) * KSTRIDE + (idx & 31) * 8] = kreg[r];
            }
            *(uint4*)&Vs[nxt][(tid >> 3) * VSTRIDE + (tid & 7) * 8] = vreg[0];
        }
        if (it + 2 < NITER) {
            const int t0 = kbase + (it + 2) * KT_;
#pragma unroll
            for (int r = 0; r < 2; r++) {
                int idx = r * 1024 + tid;
                kreg[r] = *(const uint4*)(xtb + (size_t)(t0 + (idx >> 5)) * C_ + (idx & 31) * 8);
            }
            vreg[0] = *(const uint4*)(gxb + (size_t)(tid >> 3) * N_ + t0 + (tid & 7) * 8);
        }

        // ---- St = K.Q on this group's m-half : 16 mfma / wave ----
        f4 sacc[2];
        sacc[0] = zero4; sacc[1] = zero4;
#pragma unroll
        for (int ks = 0; ks < 8; ks++) {
            bfrag ka[2];
#pragma unroll
            for (int i = 0; i < 2; i++)
                ka[i] = *(const bfrag*)&Ks[cur][(32 * g + 16 * i + ql) * KSTRIDE + 32 * ks + quad * 8];
#pragma unroll
            for (int i = 0; i < 2; i++)
                sacc[i] = __builtin_amdgcn_mfma_f32_16x16x32_bf16(ka[i], qb[ks], sacc[i], 0, 0, 0);
        }

        // ---- group-local online softmax ----
        float mx = -INFINITY;
#pragma unroll
        for (int i = 0; i < 2; i++)
#pragma unroll
            for (int r = 0; r < 4; r++) mx = fmaxf(mx, sacc[i][r]);
        mx = fmaxf(mx, __shfl_xor(mx, 16, 64));
        mx = fmaxf(mx, __shfl_xor(mx, 32, 64));
        float mn = fmaxf(mrun, mx);
        float alpha = __expf(mrun - mn);       // -inf -> 0 first iter
        mrun = mn;
        lrun *= alpha;
        if (__any(alpha != 1.f)) {
#pragma unroll
            for (int i = 0; i < 8; i++) {
                yacc[i][0] *= alpha; yacc[i][1] *= alpha;
                yacc[i][2] *= alpha; yacc[i][3] *= alpha;
            }
        }

        // ---- P = exp(S-m) -> Ps[q][m], m in group's half (wave-private) ----
        {
            int q = 16 * wq + ql;
            float lsum = 0.f;
#pragma unroll
            for (int i = 0; i < 2; i++) {
                float p0 = __expf(sacc[i][0] - mrun);
                float p1 = __expf(sacc[i][1] - mrun);
                float p2 = __expf(sacc[i][2] - mrun);
                float p3 = __expf(sacc[i][3] - mrun);
                lsum += (p0 + p1) + (p2 + p3);
                int idx = q * VSTRIDE + 32 * g + 16 * i + 4 * quad;  // m = 32g+16i+4quad+r
                unsigned long long pv = (unsigned long long)pack_bf16(p0, p1)
                                      | ((unsigned long long)pack_bf16(p2, p3) << 32);
                *(unsigned long long*)&Ps[idx] = pv;
            }
            lrun += lsum;
        }

        // ---- Yt += Vt.P over group's m-half : 8 mfma / wave ----
        {
            bfrag pb, va[8];
            pb = *(const bfrag*)&Ps[(16 * wq + ql) * VSTRIDE + 32 * g + quad * 8];
#pragma unroll
            for (int i = 0; i < 8; i++)
                va[i] = *(const bfrag*)&Vs[cur][(16 * i + ql) * VSTRIDE + 32 * g + quad * 8];
#pragma unroll
            for (int i = 0; i < 8; i++)
                yacc[i] = __builtin_amdgcn_mfma_f32_16x16x32_bf16(va[i], pb, yacc[i], 0, 0, 0);
        }

        __syncthreads();   // buf[nxt] staged; buf[cur] + Ps reads done
    }

    // ---- epilogue: merge the two m-groups (split-K algebra), store ----
    lrun += __shfl_xor(lrun, 16, 64);
    lrun += __shfl_xor(lrun, 32, 64);

    float* PsF = (float*)Ps;          // Ps dead; 18432 B = 16 KB Ysc + 2 KB mlb
    float* Ysc = PsF;                 // [32 ci'][128 q]
    float* mlb = PsF + 4096;          // [2 g][128 q][2]

    const int q = 16 * wq + ql;
    if (quad == 0) {
        mlb[(g * 128 + q) * 2]     = mrun;
        mlb[(g * 128 + q) * 2 + 1] = lrun;
    }
    __syncthreads();
    float m0 = mlb[q * 2],           l0 = mlb[q * 2 + 1];
    float m1 = mlb[(128 + q) * 2],   l1 = mlb[(128 + q) * 2 + 1];
    float mm = fmaxf(m0, m1);
    float e0 = __expf(m0 - mm), e1 = __expf(m1 - mm);
    float lnew = e0 * l0 + e1 * l1;

#pragma unroll
    for (int c = 0; c < 4; c++) {                // ci chunks of 32
        if (g == 1) {
#pragma unroll
            for (int i2 = 0; i2 < 2; i2++) {
                int i = 2 * c + i2;
#pragma unroll
                for (int r = 0; r < 4; r++) {
                    int cip = 16 * i2 + 4 * quad + r;        // ci - 32c
                    Ysc[cip * 128 + q] = e1 * yacc[i][r];
                }
            }
        }
        __syncthreads();
        if (g == 0) {
#pragma unroll
            for (int i2 = 0; i2 < 2; i2++) {
                int i = 2 * c + i2;
#pragma unroll
                for (int r = 0; r < 4; r++) {
                    int ci = 16 * i + 4 * quad + r;
                    float v = e0 * yacc[i][r] + Ysc[(16 * i2 + 4 * quad + r) * 128 + q];
                    Yp[(((size_t)half * 4 + b) * CI_ + ci) * N_ + n0 + q] = v;
                }
            }
        }
        __syncthreads();
    }
    if (g == 0 && quad == 0) {
        ml[(((size_t)half * 4 + b) * N_ + n0 + q) * 2]     = mm;
        ml[(((size_t)half * 4 + b) * N_ + n0 + q) * 2 + 1] = lnew;
    }
}

// ---------------- K5: merged split-K + W conv + BN partials (R13) --------
__global__ __launch_bounds__(256) void wconv_stats(const float* __restrict__ Yp,
                                                   const float* __restrict__ ml,
                                                   const float* __restrict__ Ww,
                                                   const float* __restrict__ Wb,
                                                   float* __restrict__ wy,
                                                   float* __restrict__ part) {
    int n   = blockIdx.x * 256 + threadIdx.x;
    int co0 = blockIdx.y * 8;
    int b   = blockIdx.z;

    // split-K merge weights for this (b, n)
    float2 a0 = *(const float2*)&ml[((size_t)b * N_ + n) * 2];
    float2 a1 = *(const float2*)&ml[(((size_t)4 + b) * N_ + n) * 2];
    float mm = fmaxf(a0.x, a1.x);
    float e0 = __expf(a0.x - mm), e1 = __expf(a1.x - mm);
    float inv = 1.f / (e0 * a0.y + e1 * a1.y);
    float w0 = e0 * inv, w1 = e1 * inv;

    const float* y0b = Yp + (size_t)b * CI_ * N_;
    const float* y1b = Yp + (size_t)(4 + b) * CI_ * N_;
    float acc[8];
#pragma unroll
    for (int o = 0; o < 8; o++) acc[o] = Wb[co0 + o];
    for (int c0 = 0; c0 < CI_; c0 += 8) {
        float yv[8];
#pragma unroll
        for (int j = 0; j < 8; j++)
            yv[j] = w0 * y0b[(c0 + j) * N_ + n] + w1 * y1b[(c0 + j) * N_ + n];
#pragma unroll
        for (int o = 0; o < 8; o++) {
            const float* wr = Ww + (size_t)(co0 + o) * CI_ + c0;
#pragma unroll
            for (int j = 0; j < 8; j++) acc[o] += wr[j] * yv[j];
        }
    }
    float* wyb = wy + (size_t)b * C_ * N_;
#pragma unroll
    for (int o = 0; o < 8; o++) wyb[(co0 + o) * N_ + n] = acc[o];

    __shared__ float wred[16][4];
    int lane = threadIdx.x & 63, wid = threadIdx.x >> 6;
#pragma unroll
    for (int o = 0; o < 8; o++) {
        float s1 = acc[o], s2 = acc[o] * acc[o];
#pragma unroll
        for (int off = 32; off > 0; off >>= 1) {
            s1 += __shfl_down(s1, off, 64);
            s2 += __shfl_down(s2, off, 64);
        }
        if (lane == 0) { wred[o][wid] = s1; wred[8 + o][wid] = s2; }
    }
    __syncthreads();
    if (threadIdx.x < 16) {
        int qq = threadIdx.x;
        float tsum = wred[qq][0] + wred[qq][1] + wred[qq][2] + wred[qq][3];
        int o = qq & 7;
        int col = b * 16 + blockIdx.x;           // 0..63
        int slot = (qq < 8 ? co0 + o : 256 + co0 + o);
        part[(size_t)slot * 64 + col] = tsum;    // non-atomic, deterministic
    }
}

// ---------------- K6: BN finalize + residual (reduce folded, R11) --------
__global__ __launch_bounds__(256) void bn_finalize(float* __restrict__ wy,
                                                   const float* __restrict__ x,
                                                   const float* __restrict__ part,
                                                   const float* __restrict__ gamma,
                                                   const float* __restrict__ beta,
                                                   float* __restrict__ out) {
    int n4 = blockIdx.x * 256 + threadIdx.x;
    int co = blockIdx.y;
    int b  = blockIdx.z;

    __shared__ float red[2];
    {
        int lane = threadIdx.x & 63, wv = threadIdx.x >> 6;
        if (wv < 2) {
            int slot = (wv == 0) ? co : 256 + co;
            float v = part[(size_t)slot * 64 + lane];
#pragma unroll
            for (int off = 32; off > 0; off >>= 1) v += __shfl_down(v, off, 64);
            if (lane == 0) red[wv] = v;
        }
    }
    __syncthreads();

    float cnt  = (float)(B_ * N_);
    float mean = red[0] / cnt;
    float var  = red[1] / cnt - mean * mean;
    float sc   = rsqrtf(var + EPS_) * gamma[co];
    float bt   = beta[co];
    size_t idx = ((size_t)b * C_ + co) * N_ + (size_t)n4 * 4;
    float4 wv4 = *(const float4*)&wy[idx];
    float4 xv  = *(const float4*)&x[idx];
    float4 o;
    o.x = (wv4.x - mean) * sc + bt + xv.x;
    o.y = (wv4.y - mean) * sc + bt + xv.y;
    o.z = (wv4.z - mean) * sc + bt + xv.z;
    o.w = (wv4.w - mean) * sc + bt + xv.w;
    *(float4*)&out[idx] = o;
}

extern "C" void kernel_launch(void* const* d_in, const int* in_sizes, int n_in,
                              void* d_out, int out_size, void* d_ws, size_t ws_size,
                              hipStream_t stream) {
    const float* x     = (const float*)d_in[0];
    const float* gw    = (const float*)d_in[1];
    const float* gb    = (const float*)d_in[2];
    const float* Ww    = (const float*)d_in[3];
    const float* Wb    = (const float*)d_in[4];
    const float* gamma = (const float*)d_in[5];
    const float* beta  = (const float*)d_in[6];
    float* out = (float*)d_out;
    float* ws  = (float*)d_ws;

    // ws (floats): total 7,406,080 = 29.6 MB (round-3 proven footprint)
    unsigned short* xt  = (unsigned short*)ws;              // 8 MB
    unsigned short* gxb = (unsigned short*)(ws + 2097152);  // 4 MB
    float* Yp   = ws + 3145728;                             // 16 MB
    float* ml   = ws + 7340032;                             // 256 KB
    float* part = ws;            // 128 KB; aliases xt (dead after attn)
    float* wy   = out;                                      // aliased onto d_out

    hipLaunchKernelGGL(gconv_xt, dim3(16, 16, 4), dim3(256), 0, stream, x, gw, gb, xt, gxb);
    hipLaunchKernelGGL(attn, dim3(256), dim3(1024), 0, stream, xt, gxb, Yp, ml);
    hipLaunchKernelGGL(wconv_stats, dim3(16, 32, 4), dim3(256), 0, stream, Yp, ml, Ww, Wb, wy, part);
    hipLaunchKernelGGL(bn_finalize, dim3(4, 256, 4), dim3(256), 0, stream, wy, x, part, gamma, beta, out);
}